// Round 7
// baseline (128.754 us; speedup 1.0000x reference)
//
#include <hip/hip_runtime.h>

// Shapes fixed by the reference: N=M=512, B=1, C=256, H=8, Dh=32, fp32.

typedef __attribute__((ext_vector_type(8))) short short8v;
typedef __attribute__((ext_vector_type(4))) float f32x4;

union PK8 { unsigned u[4]; short8v s; };

// pack bf16(hi parts) of two f32: low half = a, high half = b (truncation)
__device__ __forceinline__ unsigned pk_hi(float a, float b) {
  return __builtin_amdgcn_perm(__float_as_uint(b), __float_as_uint(a), 0x07060302u);
}
// pack bf16 of residuals (a - bf16(a)), truncation
__device__ __forceinline__ unsigned pk_lo(float a, float b) {
  float ra = a - __uint_as_float(__float_as_uint(a) & 0xFFFF0000u);
  float rb = b - __uint_as_float(__float_as_uint(b) & 0xFFFF0000u);
  return __builtin_amdgcn_perm(__float_as_uint(rb), __float_as_uint(ra), 0x07060302u);
}

// ---------------- Kernel 1: transpose Wq/Wk/Wv (256x256 each) ----------------
__global__ __launch_bounds__(256) void k_transpose(const float* __restrict__ Wq,
                                                   const float* __restrict__ Wk,
                                                   const float* __restrict__ Wv,
                                                   float* __restrict__ wt) {
  const float* W = (blockIdx.y == 0) ? Wq : (blockIdx.y == 1) ? Wk : Wv;
  float* O = wt + (size_t)blockIdx.y * 65536;
  __shared__ float t[64][65];
  const int tile = blockIdx.x;
  const int tr = (tile >> 2) * 64, tc = (tile & 3) * 64;
  const int c = threadIdx.x & 63, r0 = threadIdx.x >> 6;
#pragma unroll
  for (int i = 0; i < 16; ++i) {
    int r = r0 + i * 4;
    t[r][c] = W[(tr + r) * 256 + tc + c];
  }
  __syncthreads();
#pragma unroll
  for (int i = 0; i < 16; ++i) {
    int r = r0 + i * 4;
    O[(tc + r) * 256 + tr + c] = t[c][r];  // O[a][b] = W[b][a]
  }
}

// ---------------- Kernel 2: projections q,k,v = x @ W^T + b ----------------
__global__ __launch_bounds__(256) void k_proj(const float* __restrict__ q_in,
                                              const float* __restrict__ k_in,
                                              const float* __restrict__ v_in,
                                              const float* __restrict__ bq,
                                              const float* __restrict__ bk,
                                              const float* __restrict__ bv,
                                              const float* __restrict__ wt,
                                              float* __restrict__ outb) {
  const int mat = blockIdx.y;
  const float* x = mat == 0 ? q_in : mat == 1 ? k_in : v_in;
  const float* b = mat == 0 ? bq : mat == 1 ? bk : bv;
  const float* WT = wt + (size_t)mat * 65536;
  float* out = outb + (size_t)mat * 131072;

  __shared__ float xl[8][256];
  const int tid = threadIdx.x;
  const int n0 = blockIdx.x * 8;
  for (int idx = tid; idx < 2048; idx += 256)
    xl[idx >> 8][idx & 255] = x[(n0 + (idx >> 8)) * 256 + (idx & 255)];
  __syncthreads();

  float acc[8] = {0.f, 0.f, 0.f, 0.f, 0.f, 0.f, 0.f, 0.f};
  for (int j = 0; j < 256; j += 4) {
    const float w0 = WT[(j + 0) * 256 + tid];
    const float w1 = WT[(j + 1) * 256 + tid];
    const float w2 = WT[(j + 2) * 256 + tid];
    const float w3 = WT[(j + 3) * 256 + tid];
#pragma unroll
    for (int r = 0; r < 8; ++r) {
      const float4 xv = *(const float4*)&xl[r][j];
      acc[r] += xv.x * w0 + xv.y * w1 + xv.z * w2 + xv.w * w3;
    }
  }
  const float bb = b[tid];
#pragma unroll
  for (int r = 0; r < 8; ++r) out[(n0 + r) * 256 + tid] = acc[r] + bb;
}

// ---------------- Kernel 3: t[n][h][j] (pre-scaled by 1/sqrt(Dh)); qb likewise ----------------
__global__ __launch_bounds__(256) void k_tfold(const float* __restrict__ qkv,
                                               const float* __restrict__ Wg,
                                               const float* __restrict__ bg,
                                               float* __restrict__ t_ws,
                                               float* __restrict__ qb_ws) {
  const int h = blockIdx.y;
  const int n0 = blockIdx.x * 64;
  const int tid = threadIdx.x;
  const float scale = 0.17677669529663687f;  // 1/sqrt(32)
  __shared__ float wg_s[32][256];
  __shared__ float qs[64][32];
  __shared__ float bgs[32];

  for (int idx = tid; idx < 8192; idx += 256)
    wg_s[idx >> 8][idx & 255] = Wg[(size_t)(h * 32 + (idx >> 8)) * 256 + (idx & 255)];
  for (int idx = tid; idx < 2048; idx += 256)
    qs[idx >> 5][idx & 31] = qkv[(size_t)(n0 + (idx >> 5)) * 256 + h * 32 + (idx & 31)];
  if (tid < 32) bgs[tid] = bg[h * 32 + tid];
  __syncthreads();

  float wr[32];
#pragma unroll
  for (int i = 0; i < 32; ++i) wr[i] = wg_s[i][tid];
  for (int nn = 0; nn < 64; ++nn) {
    float a = 0.f;
#pragma unroll
    for (int i = 0; i < 32; ++i) a = fmaf(qs[nn][i], wr[i], a);
    t_ws[(size_t)(n0 + nn) * 2048 + h * 256 + tid] = a * scale;
  }
  if (tid < 64) {
    float a = 0.f;
#pragma unroll
    for (int i = 0; i < 32; ++i) a = fmaf(qs[tid][i], bgs[i], a);
    qb_ws[(n0 + tid) * 8 + h] = a * scale;
  }
}

// ---------------- Kernel 4: scores via bf16x3 MFMA for one (n, m-chunk of 128) ----------------
// grid (512, 4), 256 threads = 4 waves; wave w owns 32 rows (2 MFMA M-tiles).
// Augmented GEMM: scores[h, m] = sum_{k=0..511} A[m,k] * B[k,h]
//   A = [E[n,m,0:256] | k_proj[m,0:256]],  B = [t_scaled | q_masked_scaled] (bf16 hi+lo)
// B in LDS: rows = 16 cols of MFMA-N (heads 0-7 live, 8-15 zero), stride 260 words.
// mfma_f32_16x16x32_bf16, frag elem i <-> k = (i>>2)*16 + (lane>>4)*4 + (i&3).
__global__ __launch_bounds__(256) void k_scores(const float* __restrict__ Eg,
                                                const float* __restrict__ qkv,
                                                const float* __restrict__ t_ws,
                                                const float* __restrict__ qb_ws,
                                                float* __restrict__ attn_raw) {
  const int n = blockIdx.x, mb = blockIdx.y;
  const int tid = threadIdx.x;
  const int lane = tid & 63, w = tid >> 6;
  const int g = lane >> 4, rw = lane & 15;
  const float* k_g = qkv + 131072;
  const float scale = 0.17677669529663687f;

  __shared__ unsigned lds_hi[4160];  // [16 cols][260 words] packed bf16 pairs
  __shared__ unsigned lds_lo[4160];
  __shared__ float p_lds[1064];      // [8][133]

  // ---- build B (zero, then fill t rows 0-7 words 0-127, masked q words 128-255) ----
  for (int idx = tid; idx < 4160; idx += 256) { lds_hi[idx] = 0u; lds_lo[idx] = 0u; }
  __syncthreads();
  for (int idx = tid; idx < 1024; idx += 256) {
    const int r = idx >> 7, wd = idx & 127;
    const float2 f = *(const float2*)(t_ws + (size_t)n * 2048 + r * 256 + wd * 2);
    lds_hi[r * 260 + wd] = pk_hi(f.x, f.y);
    lds_lo[r * 260 + wd] = pk_lo(f.x, f.y);
  }
  if (tid < 128) {
    const int r = tid >> 4, w16 = tid & 15;
    const int wq = r * 16 + w16;                 // word within q-part
    float2 f = *(const float2*)(qkv + n * 256 + wq * 2);
    f.x *= scale; f.y *= scale;
    lds_hi[r * 260 + 128 + wq] = pk_hi(f.x, f.y);
    lds_lo[r * 260 + 128 + wq] = pk_lo(f.x, f.y);
  }
  float qb_r[8];
#pragma unroll
  for (int h = 0; h < 8; ++h) qb_r[h] = qb_ws[n * 8 + h];
  __syncthreads();

  const int m_base = mb * 128 + w * 32;
  const float* A0 = Eg + ((size_t)n * 512 + m_base + rw) * 256 + g * 4;   // tile0 row
  const float* K0 = k_g + (size_t)(m_base + rw) * 256 + g * 4;

  f32x4 acc0 = {0.f, 0.f, 0.f, 0.f};
  f32x4 acc1 = {0.f, 0.f, 0.f, 0.f};

#define DO_CHUNK(AP0, AP1, WB)                                                 \
  {                                                                            \
    const uint2 bh1 = *(const uint2*)&lds_hi[rw * 260 + (WB) + g * 2];         \
    const uint2 bh2 = *(const uint2*)&lds_hi[rw * 260 + (WB) + 8 + g * 2];     \
    const uint2 bl1 = *(const uint2*)&lds_lo[rw * 260 + (WB) + g * 2];         \
    const uint2 bl2 = *(const uint2*)&lds_lo[rw * 260 + (WB) + 8 + g * 2];     \
    PK8 Bh, Bl;                                                                \
    Bh.u[0] = bh1.x; Bh.u[1] = bh1.y; Bh.u[2] = bh2.x; Bh.u[3] = bh2.y;        \
    Bl.u[0] = bl1.x; Bl.u[1] = bl1.y; Bl.u[2] = bl2.x; Bl.u[3] = bl2.y;        \
    const float4 a0a = *(const float4*)(AP0);                                  \
    const float4 a0b = *(const float4*)(AP0 + 16);                             \
    const float4 a1a = *(const float4*)(AP1);                                  \
    const float4 a1b = *(const float4*)(AP1 + 16);                             \
    PK8 A0h, A0l, A1h, A1l;                                                    \
    A0h.u[0] = pk_hi(a0a.x, a0a.y); A0h.u[1] = pk_hi(a0a.z, a0a.w);            \
    A0h.u[2] = pk_hi(a0b.x, a0b.y); A0h.u[3] = pk_hi(a0b.z, a0b.w);            \
    A0l.u[0] = pk_lo(a0a.x, a0a.y); A0l.u[1] = pk_lo(a0a.z, a0a.w);            \
    A0l.u[2] = pk_lo(a0b.x, a0b.y); A0l.u[3] = pk_lo(a0b.z, a0b.w);            \
    A1h.u[0] = pk_hi(a1a.x, a1a.y); A1h.u[1] = pk_hi(a1a.z, a1a.w);            \
    A1h.u[2] = pk_hi(a1b.x, a1b.y); A1h.u[3] = pk_hi(a1b.z, a1b.w);            \
    A1l.u[0] = pk_lo(a1a.x, a1a.y); A1l.u[1] = pk_lo(a1a.z, a1a.w);            \
    A1l.u[2] = pk_lo(a1b.x, a1b.y); A1l.u[3] = pk_lo(a1b.z, a1b.w);            \
    acc0 = __builtin_amdgcn_mfma_f32_16x16x32_bf16(A0h.s, Bh.s, acc0, 0, 0, 0);\
    acc0 = __builtin_amdgcn_mfma_f32_16x16x32_bf16(A0l.s, Bh.s, acc0, 0, 0, 0);\
    acc0 = __builtin_amdgcn_mfma_f32_16x16x32_bf16(A0h.s, Bl.s, acc0, 0, 0, 0);\
    acc1 = __builtin_amdgcn_mfma_f32_16x16x32_bf16(A1h.s, Bh.s, acc1, 0, 0, 0);\
    acc1 = __builtin_amdgcn_mfma_f32_16x16x32_bf16(A1l.s, Bh.s, acc1, 0, 0, 0);\
    acc1 = __builtin_amdgcn_mfma_f32_16x16x32_bf16(A1h.s, Bl.s, acc1, 0, 0, 0);\
  }

  // E chunks: k = 0..255  (HBM stream)
#pragma unroll 4
  for (int kc = 0; kc < 8; ++kc) {
    DO_CHUNK(A0 + kc * 32, A0 + 16 * 256 + kc * 32, kc * 16)
  }
  // K chunks: k = 256..511 (L2-resident k projection)
#pragma unroll 2
  for (int kc = 0; kc < 8; ++kc) {
    DO_CHUNK(K0 + kc * 32, K0 + 16 * 256 + kc * 32, 128 + kc * 16)
  }
#undef DO_CHUNK

  // ---- epilogue: C col = lane&15 (head), row = g*4 + reg (+16 for tile1) ----
  if (rw < 8) {
    const int ml = w * 32 + g * 4;
#pragma unroll
    for (int r2 = 0; r2 < 4; ++r2) {
      p_lds[rw * 133 + ml + r2] = acc0[r2];
      p_lds[rw * 133 + 16 + ml + r2] = acc1[r2];
    }
  }
  __syncthreads();
  for (int idx = tid; idx < 1024; idx += 256) {
    const int hh = idx >> 7, mm = idx & 127;
    attn_raw[(size_t)hh * 262144 + n * 512 + mb * 128 + mm] = p_lds[hh * 133 + mm] + qb_r[hh];
  }
}

// ---------------- Kernel 5: softmax + attn normalize (in-place) + attn@v ----------------
// grid 512 (one per n), 512 threads = 8 waves (wave w = head w for softmax).
__global__ __launch_bounds__(512) void k_finish(const float* __restrict__ qkv,
                                                float* __restrict__ out) {
  const float* v_g = qkv + 262144;
  const int n = blockIdx.x, tid = threadIdx.x;
  const int lane = tid & 63, w = tid >> 6;
  float* attn = out + 131072;

  __shared__ float sc[4096];     // [8 heads][512 m]
  __shared__ float invd[8];
  __shared__ float pv[2][256];

  {
    float4* d = (float4*)sc;
    int i0 = tid;
    d[i0] = *(const float4*)(attn + (size_t)(i0 >> 7) * 262144 + n * 512 + (i0 & 127) * 4);
    int i1 = tid + 512;
    d[i1] = *(const float4*)(attn + (size_t)(i1 >> 7) * 262144 + n * 512 + (i1 & 127) * 4);
  }
  __syncthreads();

  // softmax over m for head w
  {
    float vals[8];
#pragma unroll
    for (int i = 0; i < 8; ++i) vals[i] = sc[w * 512 + lane + i * 64];
    float mx = vals[0];
#pragma unroll
    for (int i = 1; i < 8; ++i) mx = fmaxf(mx, vals[i]);
#pragma unroll
    for (int off = 1; off < 64; off <<= 1) mx = fmaxf(mx, __shfl_xor(mx, off));
    float sum = 0.f;
#pragma unroll
    for (int i = 0; i < 8; ++i) {
      const float e = __expf(vals[i] - mx);
      sum += e;
      sc[w * 512 + lane + i * 64] = e;
    }
#pragma unroll
    for (int off = 1; off < 64; off <<= 1) sum += __shfl_xor(sum, off);
    if (lane == 0) invd[w] = 1.f / sum;
  }
  __syncthreads();

  // normalized attn write (in-place over raw scores)
#pragma unroll
  for (int r = 0; r < 8; ++r) {
    const int idx = tid + r * 512;
    const int h = idx >> 9, m = idx & 511;
    attn[(size_t)h * 262144 + n * 512 + m] = sc[idx] * invd[h];
  }

  // hidden[n,c] = (sum_m p[h][m] * v[m,c]) * invd[h]; split m across 2 thread-halves
  const int c = tid & 255, half = tid >> 8, h2 = c >> 5;
  const float* pr = sc + h2 * 512 + half * 256;
  const float* vp = v_g + (size_t)half * 65536 + c;
  float acc = 0.f;
#pragma unroll 4
  for (int m4 = 0; m4 < 64; ++m4) {
    const float4 p4 = *(const float4*)(pr + m4 * 4);
    const int mb = m4 * 4;
    acc = fmaf(p4.x, vp[(size_t)(mb + 0) * 256], acc);
    acc = fmaf(p4.y, vp[(size_t)(mb + 1) * 256], acc);
    acc = fmaf(p4.z, vp[(size_t)(mb + 2) * 256], acc);
    acc = fmaf(p4.w, vp[(size_t)(mb + 3) * 256], acc);
  }
  pv[half][c] = acc;
  __syncthreads();
  if (tid < 256) out[n * 256 + tid] = (pv[0][tid] + pv[1][tid]) * invd[tid >> 5];
}

extern "C" void kernel_launch(void* const* d_in, const int* in_sizes, int n_in,
                              void* d_out, int out_size, void* d_ws, size_t ws_size,
                              hipStream_t stream) {
  const float* query = (const float*)d_in[0];
  const float* key   = (const float*)d_in[1];
  const float* value = (const float*)d_in[2];
  const float* Eg    = (const float*)d_in[3];
  const float* Wq    = (const float*)d_in[4];
  const float* bq    = (const float*)d_in[5];
  const float* Wk    = (const float*)d_in[6];
  const float* bk    = (const float*)d_in[7];
  const float* Wv    = (const float*)d_in[8];
  const float* bv    = (const float*)d_in[9];
  const float* Wg    = (const float*)d_in[10];
  const float* bg    = (const float*)d_in[11];
  float* out = (float*)d_out;

  // ws layout (floats): wt[3*65536] | qkv[3*131072] | t_ws[512*2048] | qb_ws[4096]  ≈ 6.6 MB
  float* ws = (float*)d_ws;
  float* wt = ws;
  float* qkv = wt + 3 * 65536;
  float* t_ws = qkv + 3 * 131072;
  float* qb_ws = t_ws + 512 * 2048;

  k_transpose<<<dim3(16, 3), 256, 0, stream>>>(Wq, Wk, Wv, wt);
  k_proj<<<dim3(64, 3), 256, 0, stream>>>(query, key, value, bq, bk, bv, wt, qkv);
  k_tfold<<<dim3(8, 8), 256, 0, stream>>>(qkv, Wg, bg, t_ws, qb_ws);
  k_scores<<<dim3(512, 4), 256, 0, stream>>>(Eg, qkv, t_ws, qb_ws, out + 131072);
  k_finish<<<dim3(512), 512, 0, stream>>>(qkv, out);
}

// Round 8
// 105.754 us; speedup vs baseline: 1.2175x; 1.2175x over previous
//
#include <hip/hip_runtime.h>

// Shapes fixed by the reference: N=M=512, B=1, C=256, H=8, Dh=32, fp32.

// DPP-based add-exchange (pure VALU, avoids ds_swizzle / LDS pipe).
template <int CTRL, int RMASK>
__device__ __forceinline__ float dpp_add(float v) {
  int x = __builtin_amdgcn_update_dpp(0, __float_as_int(v), CTRL, RMASK, 0xf, false);
  return v + __int_as_float(x);
}

// ---------------- Kernel 1: transpose Wq/Wk/Wv (256x256 each) ----------------
__global__ __launch_bounds__(256) void k_transpose(const float* __restrict__ Wq,
                                                   const float* __restrict__ Wk,
                                                   const float* __restrict__ Wv,
                                                   float* __restrict__ wt) {
  const float* W = (blockIdx.y == 0) ? Wq : (blockIdx.y == 1) ? Wk : Wv;
  float* O = wt + (size_t)blockIdx.y * 65536;
  __shared__ float t[64][65];
  const int tile = blockIdx.x;
  const int tr = (tile >> 2) * 64, tc = (tile & 3) * 64;
  const int c = threadIdx.x & 63, r0 = threadIdx.x >> 6;
#pragma unroll
  for (int i = 0; i < 16; ++i) {
    int r = r0 + i * 4;
    t[r][c] = W[(tr + r) * 256 + tc + c];
  }
  __syncthreads();
#pragma unroll
  for (int i = 0; i < 16; ++i) {
    int r = r0 + i * 4;
    O[(tc + r) * 256 + tr + c] = t[c][r];  // O[a][b] = W[b][a]
  }
}

// ---------------- Kernel 2: projections q,k,v = x @ W^T + b ----------------
__global__ __launch_bounds__(256) void k_proj(const float* __restrict__ q_in,
                                              const float* __restrict__ k_in,
                                              const float* __restrict__ v_in,
                                              const float* __restrict__ bq,
                                              const float* __restrict__ bk,
                                              const float* __restrict__ bv,
                                              const float* __restrict__ wt,
                                              float* __restrict__ outb) {
  const int mat = blockIdx.y;
  const float* x = mat == 0 ? q_in : mat == 1 ? k_in : v_in;
  const float* b = mat == 0 ? bq : mat == 1 ? bk : bv;
  const float* WT = wt + (size_t)mat * 65536;
  float* out = outb + (size_t)mat * 131072;

  __shared__ float xl[8][256];
  const int tid = threadIdx.x;
  const int n0 = blockIdx.x * 8;
  for (int idx = tid; idx < 2048; idx += 256)
    xl[idx >> 8][idx & 255] = x[(n0 + (idx >> 8)) * 256 + (idx & 255)];
  __syncthreads();

  float acc[8] = {0.f, 0.f, 0.f, 0.f, 0.f, 0.f, 0.f, 0.f};
  for (int j = 0; j < 256; j += 4) {
    const float w0 = WT[(j + 0) * 256 + tid];
    const float w1 = WT[(j + 1) * 256 + tid];
    const float w2 = WT[(j + 2) * 256 + tid];
    const float w3 = WT[(j + 3) * 256 + tid];
#pragma unroll
    for (int r = 0; r < 8; ++r) {
      const float4 xv = *(const float4*)&xl[r][j];
      acc[r] += xv.x * w0 + xv.y * w1 + xv.z * w2 + xv.w * w3;
    }
  }
  const float bb = b[tid];
#pragma unroll
  for (int r = 0; r < 8; ++r) out[(n0 + r) * 256 + tid] = acc[r] + bb;
}

// ---------------- Kernel 3: t[n][h][j] (pre-scaled by 1/sqrt(Dh)); qb likewise ----------------
__global__ __launch_bounds__(256) void k_tfold(const float* __restrict__ qkv,
                                               const float* __restrict__ Wg,
                                               const float* __restrict__ bg,
                                               float* __restrict__ t_ws,
                                               float* __restrict__ qb_ws) {
  const int h = blockIdx.y;
  const int n0 = blockIdx.x * 64;
  const int tid = threadIdx.x;
  const float scale = 0.17677669529663687f;  // 1/sqrt(32)
  __shared__ float wg_s[32][256];
  __shared__ float qs[64][32];
  __shared__ float bgs[32];

  for (int idx = tid; idx < 8192; idx += 256)
    wg_s[idx >> 8][idx & 255] = Wg[(size_t)(h * 32 + (idx >> 8)) * 256 + (idx & 255)];
  for (int idx = tid; idx < 2048; idx += 256)
    qs[idx >> 5][idx & 31] = qkv[(size_t)(n0 + (idx >> 5)) * 256 + h * 32 + (idx & 31)];
  if (tid < 32) bgs[tid] = bg[h * 32 + tid];
  __syncthreads();

  float wr[32];
#pragma unroll
  for (int i = 0; i < 32; ++i) wr[i] = wg_s[i][tid];
  for (int nn = 0; nn < 64; ++nn) {
    float a = 0.f;
#pragma unroll
    for (int i = 0; i < 32; ++i) a = fmaf(qs[nn][i], wr[i], a);
    t_ws[(size_t)(n0 + nn) * 2048 + h * 256 + tid] = a * scale;
  }
  if (tid < 64) {
    float a = 0.f;
#pragma unroll
    for (int i = 0; i < 32; ++i) a = fmaf(qs[tid][i], bgs[i], a);
    qb_ws[(n0 + tid) * 8 + h] = a * scale;
  }
}

// ---------------- Kernel 4: FUSED scores + softmax + attn + attn@v, one block per n ----------------
// 512 threads = 8 waves. Stream phase: wave w owns m-rows [w*64, w*64+64), 2
// rows/iter (one per 32-lane half); 32 lanes/row, 8 channels/lane; t fragment
// (8h x 8ch, pre-scaled) in 64 regs; K folded in via mask trick (round-5
// structure, 113us best). DPP 32-lane reduce. Then softmax (wave w = head w),
// normalized attn write, and PV — all from LDS sc[8][512]; no attn_raw
// round-trip. __launch_bounds__(512,4) pins VGPR<=128 for 4 waves/SIMD
// (budget ~120 live; small forcing gap, unlike round-2's 40+ reg disaster).
__global__ __launch_bounds__(512, 4) void k_main(const float* __restrict__ Eg,
                                                 const float* __restrict__ qkv,
                                                 const float* __restrict__ t_ws,
                                                 const float* __restrict__ qb_ws,
                                                 float* __restrict__ out) {
  const float* k_g = qkv + 131072;
  const float* v_g = qkv + 262144;
  const int n = blockIdx.x;
  const int tid = threadIdx.x;
  const int lane = tid & 63, w = tid >> 6;
  const int s = lane & 31, g = lane >> 5;
  const float scale = 0.17677669529663687f;  // 1/sqrt(32)
  float* attn = out + 131072;

  __shared__ float sc[4096];   // [8 heads][512 m] raw-then-exp scores
  __shared__ float invd[8];
  __shared__ float pv[2][256];

  // t fragment: 8 heads x this lane's 8 channels (pre-scaled; L2-resident)
  float t_r[8][8];
#pragma unroll
  for (int h = 0; h < 8; ++h) {
    const float4 a = *(const float4*)(t_ws + (size_t)n * 2048 + h * 256 + s * 8);
    const float4 b = *(const float4*)(t_ws + (size_t)n * 2048 + h * 256 + s * 8 + 4);
    t_r[h][0] = a.x; t_r[h][1] = a.y; t_r[h][2] = a.z; t_r[h][3] = a.w;
    t_r[h][4] = b.x; t_r[h][5] = b.y; t_r[h][6] = b.z; t_r[h][7] = b.w;
  }
  // q fragment, pre-scaled (so masked kacc lands scaled)
  float q_r[8];
  {
    const float4 a = *(const float4*)(qkv + n * 256 + s * 8);
    const float4 b = *(const float4*)(qkv + n * 256 + s * 8 + 4);
    q_r[0] = a.x * scale; q_r[1] = a.y * scale; q_r[2] = a.z * scale; q_r[3] = a.w * scale;
    q_r[4] = b.x * scale; q_r[5] = b.y * scale; q_r[6] = b.z * scale; q_r[7] = b.w * scale;
  }
  float qb_r[8];
#pragma unroll
  for (int h = 0; h < 8; ++h) qb_r[h] = qb_ws[n * 8 + h];  // uniform -> scalar
  float msk[8];
#pragma unroll
  for (int h = 0; h < 8; ++h) msk[h] = ((s >> 2) == h) ? 1.f : 0.f;

  // ---- stream phase: rows w*64 + it*2 + g ----
  const float* E0 = Eg + ((size_t)n * 512 + w * 64 + g) * 256 + s * 8;
  const float* K0 = k_g + (size_t)(w * 64 + g) * 256 + s * 8;
  int m = w * 64 + g;

#pragma unroll 2
  for (int it = 0; it < 32; ++it) {
    const float4 e0 = *(const float4*)(E0);
    const float4 e1 = *(const float4*)(E0 + 4);
    const float4 k0 = *(const float4*)(K0);
    const float4 k1 = *(const float4*)(K0 + 4);
    // k-dot partial: this lane's channels all belong to head s>>2
    float kacc;
    kacc = k0.x * q_r[0];             kacc = fmaf(k0.y, q_r[1], kacc);
    kacc = fmaf(k0.z, q_r[2], kacc);  kacc = fmaf(k0.w, q_r[3], kacc);
    kacc = fmaf(k1.x, q_r[4], kacc);  kacc = fmaf(k1.y, q_r[5], kacc);
    kacc = fmaf(k1.z, q_r[6], kacc);  kacc = fmaf(k1.w, q_r[7], kacc);
#pragma unroll
    for (int h = 0; h < 8; ++h) {
      float v = msk[h] * kacc;
      v = fmaf(e0.x, t_r[h][0], v); v = fmaf(e0.y, t_r[h][1], v);
      v = fmaf(e0.z, t_r[h][2], v); v = fmaf(e0.w, t_r[h][3], v);
      v = fmaf(e1.x, t_r[h][4], v); v = fmaf(e1.y, t_r[h][5], v);
      v = fmaf(e1.z, t_r[h][6], v); v = fmaf(e1.w, t_r[h][7], v);
      // 32-lane reduce: xor1, xor2, half_mirror(xor4), mirror(xor8),
      // bcast15 folds row0 into row1 (valid lanes 16-31 / 48-63).
      v = dpp_add<0xB1, 0xf>(v);
      v = dpp_add<0x4E, 0xf>(v);
      v = dpp_add<0x141, 0xf>(v);
      v = dpp_add<0x140, 0xf>(v);
      v = dpp_add<0x142, 0xa>(v);
      if (s == 16 + h) sc[h * 512 + m] = v + qb_r[h];
    }
    E0 += 512; K0 += 512; m += 2;
  }
  __syncthreads();

  // ---- softmax over m for head w ----
  {
    float vals[8];
#pragma unroll
    for (int i = 0; i < 8; ++i) vals[i] = sc[w * 512 + lane + i * 64];
    float mx = vals[0];
#pragma unroll
    for (int i = 1; i < 8; ++i) mx = fmaxf(mx, vals[i]);
#pragma unroll
    for (int off = 1; off < 64; off <<= 1) mx = fmaxf(mx, __shfl_xor(mx, off));
    float sum = 0.f;
#pragma unroll
    for (int i = 0; i < 8; ++i) {
      const float e = __expf(vals[i] - mx);
      sum += e;
      sc[w * 512 + lane + i * 64] = e;
    }
#pragma unroll
    for (int off = 1; off < 64; off <<= 1) sum += __shfl_xor(sum, off);
    if (lane == 0) invd[w] = 1.f / sum;
  }
  __syncthreads();

  // ---- normalized attn write ----
#pragma unroll
  for (int r = 0; r < 8; ++r) {
    const int idx = tid + r * 512;
    const int h = idx >> 9, mm = idx & 511;
    attn[(size_t)h * 262144 + n * 512 + mm] = sc[idx] * invd[h];
  }

  // ---- hidden[n,c] = (sum_m p[h][m] * v[m,c]) * invd[h]; m split across halves ----
  const int c = tid & 255, half = tid >> 8, h2 = c >> 5;
  const float* pr = sc + h2 * 512 + half * 256;
  const float* vp = v_g + (size_t)half * 65536 + c;
  float acc = 0.f;
#pragma unroll 4
  for (int m4 = 0; m4 < 64; ++m4) {
    const float4 p4 = *(const float4*)(pr + m4 * 4);
    const int mb = m4 * 4;
    acc = fmaf(p4.x, vp[(size_t)(mb + 0) * 256], acc);
    acc = fmaf(p4.y, vp[(size_t)(mb + 1) * 256], acc);
    acc = fmaf(p4.z, vp[(size_t)(mb + 2) * 256], acc);
    acc = fmaf(p4.w, vp[(size_t)(mb + 3) * 256], acc);
  }
  pv[half][c] = acc;
  __syncthreads();
  if (tid < 256) out[n * 256 + tid] = (pv[0][tid] + pv[1][tid]) * invd[tid >> 5];
}

extern "C" void kernel_launch(void* const* d_in, const int* in_sizes, int n_in,
                              void* d_out, int out_size, void* d_ws, size_t ws_size,
                              hipStream_t stream) {
  const float* query = (const float*)d_in[0];
  const float* key   = (const float*)d_in[1];
  const float* value = (const float*)d_in[2];
  const float* Eg    = (const float*)d_in[3];
  const float* Wq    = (const float*)d_in[4];
  const float* bq    = (const float*)d_in[5];
  const float* Wk    = (const float*)d_in[6];
  const float* bk    = (const float*)d_in[7];
  const float* Wv    = (const float*)d_in[8];
  const float* bv    = (const float*)d_in[9];
  const float* Wg    = (const float*)d_in[10];
  const float* bg    = (const float*)d_in[11];
  float* out = (float*)d_out;

  // ws layout (floats): wt[3*65536] | qkv[3*131072] | t_ws[512*2048] | qb_ws[4096]  ≈ 6.6 MB
  float* ws = (float*)d_ws;
  float* wt = ws;
  float* qkv = wt + 3 * 65536;
  float* t_ws = qkv + 3 * 131072;
  float* qb_ws = t_ws + 512 * 2048;

  k_transpose<<<dim3(16, 3), 256, 0, stream>>>(Wq, Wk, Wv, wt);
  k_proj<<<dim3(64, 3), 256, 0, stream>>>(query, key, value, bq, bk, bv, wt, qkv);
  k_tfold<<<dim3(8, 8), 256, 0, stream>>>(qkv, Wg, bg, t_ws, qb_ws);
  k_main<<<dim3(512), 512, 0, stream>>>(Eg, qkv, t_ws, qb_ws, out);
}